// Round 1
// baseline (392.433 us; speedup 1.0000x reference)
//
#include <hip/hip_runtime.h>

// ---------------------------------------------------------------------------
// CasualMultiQueryAttention: x->(Q,K,V) proj + RoPE, causal flash attention,
// output projection. B=2,S=2048,D=2048,H=16,HD=128. bf16 MFMA compute.
// ---------------------------------------------------------------------------

typedef __attribute__((ext_vector_type(8))) short short8;
typedef __attribute__((ext_vector_type(4))) float f32x4;
typedef __attribute__((ext_vector_type(4))) unsigned short u16x4;
typedef __attribute__((ext_vector_type(8))) unsigned short u16x8;

constexpr int Bc = 2, Sc = 2048, Dc = 2048, Hc = 16, HDc = 128;
constexpr int Mc = Bc * Sc;            // 4096 rows
constexpr int Nc = Dc, Kc = Dc;        // 2048

__device__ __forceinline__ unsigned short f2bf(float f) {
    union { float f; unsigned u; } x; x.f = f;
    unsigned r = x.u + 0x7FFFu + ((x.u >> 16) & 1u);   // RNE
    return (unsigned short)(r >> 16);
}

__device__ __forceinline__ void g2lds16(const void* g, void* l) {
    __builtin_amdgcn_global_load_lds(
        (const __attribute__((address_space(1))) void*)g,
        (__attribute__((address_space(3))) void*)l, 16, 0, 0);
}

// --------------------------- fp32 -> bf16 convert ---------------------------
__global__ __launch_bounds__(256) void cvt_f32_bf16(
    const float* __restrict__ in, unsigned short* __restrict__ out, int n8) {
    int i = blockIdx.x * 256 + threadIdx.x;
    if (i >= n8) return;
    f32x4 a = *((const f32x4*)in + (size_t)i * 2);
    f32x4 b = *((const f32x4*)in + (size_t)i * 2 + 1);
    u16x8 o;
    o[0] = f2bf(a[0]); o[1] = f2bf(a[1]); o[2] = f2bf(a[2]); o[3] = f2bf(a[3]);
    o[4] = f2bf(b[0]); o[5] = f2bf(b[1]); o[6] = f2bf(b[2]); o[7] = f2bf(b[3]);
    *((u16x8*)out + i) = o;
}

// --------------------------- NT GEMM, fused epilogues ------------------------
// C[M][N] = A[M][K] * W[N][K]^T + bias
// MODE 0: RoPE -> bf16 q    MODE 1: RoPE -> bf16 k
// MODE 2: -> bf16 V^T [B][D][S]   MODE 3: -> fp32 out
template <int MODE>
__global__ __launch_bounds__(256) void gemm_nt(
    const unsigned short* __restrict__ A, const unsigned short* __restrict__ W,
    const float* __restrict__ bias, const float* __restrict__ rc,
    const float* __restrict__ rs, void* __restrict__ outp) {
    __shared__ __align__(16) unsigned short As[128 * 64];
    __shared__ __align__(16) unsigned short Bs[128 * 64];
    const int tid = threadIdx.x;
    const int w = tid >> 6, l = tid & 63;
    const int wm = w >> 1, wn = w & 1;
    const int lrow = l & 15, lhi = l >> 4;
    const int m0 = blockIdx.y * 128, n0 = blockIdx.x * 128;

    f32x4 acc[4][4];
#pragma unroll
    for (int i = 0; i < 4; ++i)
#pragma unroll
        for (int j = 0; j < 4; ++j) acc[i][j] = (f32x4){0.f, 0.f, 0.f, 0.f};

    for (int k0 = 0; k0 < Kc; k0 += 64) {
        __syncthreads();
#pragma unroll
        for (int i = 0; i < 4; ++i) {
            int s = i * 256 + tid;
            int row = s >> 3, c = s & 7;
            int cg = (c ^ (row & 7)) * 8;      // pre-swizzled global source
            g2lds16(A + (size_t)(m0 + row) * Kc + k0 + cg,
                    &As[(size_t)(i * 256 + (w << 6)) * 8]);
            g2lds16(W + (size_t)(n0 + row) * Kc + k0 + cg,
                    &Bs[(size_t)(i * 256 + (w << 6)) * 8]);
        }
        __syncthreads();
#pragma unroll
        for (int kk = 0; kk < 2; ++kk) {
            short8 af[4], bf[4];
#pragma unroll
            for (int i = 0; i < 4; ++i) {
                int ra = wm * 64 + i * 16 + lrow;
                af[i] = *(const short8*)&As[ra * 64 + (((kk * 4 + lhi) ^ (ra & 7)) << 3)];
                int rb = wn * 64 + i * 16 + lrow;
                bf[i] = *(const short8*)&Bs[rb * 64 + (((kk * 4 + lhi) ^ (rb & 7)) << 3)];
            }
#pragma unroll
            for (int i = 0; i < 4; ++i)
#pragma unroll
                for (int j = 0; j < 4; ++j)
                    acc[i][j] = __builtin_amdgcn_mfma_f32_16x16x32_bf16(
                        af[i], bf[j], acc[i][j], 0, 0, 0);
        }
    }

#pragma unroll
    for (int i = 0; i < 4; ++i) {
#pragma unroll
        for (int j = 0; j < 4; ++j) {
            int gm0 = m0 + wm * 64 + i * 16 + lhi * 4;
            int gn  = n0 + wn * 64 + j * 16 + lrow;
            float bv = bias[gn];
            if (MODE == 0 || MODE == 1) {
                unsigned short* o = (unsigned short*)outp;
                int fi = (gn & (HDc - 1)) >> 1;
#pragma unroll
                for (int r = 0; r < 4; ++r) {
                    int gm = gm0 + r;
                    float v = acc[i][j][r] + bv;
                    float p = __shfl_xor(v, 1);          // partner column gn^1
                    int pos = gm & (Sc - 1);
                    float cz = rc[pos * (HDc / 2) + fi];
                    float sz = rs[pos * (HDc / 2) + fi];
                    float ov = (gn & 1) ? (p * sz + v * cz) : (v * cz - p * sz);
                    o[(size_t)gm * Nc + gn] = f2bf(ov);
                }
            } else if (MODE == 2) {
                unsigned short* o = (unsigned short*)outp;   // V^T [B][D][S]
                int b = gm0 >> 11, sb = gm0 & (Sc - 1);
                u16x4 pk;
#pragma unroll
                for (int r = 0; r < 4; ++r) pk[r] = f2bf(acc[i][j][r] + bv);
                *(u16x4*)&o[((size_t)b * Dc + gn) * Sc + sb] = pk;
            } else {
                float* o = (float*)outp;
#pragma unroll
                for (int r = 0; r < 4; ++r)
                    o[(size_t)(gm0 + r) * Nc + gn] = acc[i][j][r] + bv;
            }
        }
    }
}

// --------------------------- causal flash attention -------------------------
// grid: (S/64, B*H); 256 threads = 4 waves, each wave owns 16 q rows.
__global__ __launch_bounds__(256) void attn_fwd(
    const unsigned short* __restrict__ Q, const unsigned short* __restrict__ Kb,
    const unsigned short* __restrict__ Vt, unsigned short* __restrict__ O) {
    __shared__ __align__(16) unsigned short Ks[64 * 128];
    __shared__ __align__(16) unsigned short Vs[128 * 64];
    __shared__ __align__(16) unsigned short Ps[4 * 16 * 64];
    const int tid = threadIdx.x;
    const int w = tid >> 6, l = tid & 63;
    const int lrow = l & 15, lhi = l >> 4;
    const int qt = blockIdx.x;
    const int b = blockIdx.y >> 4, h = blockIdx.y & 15;

    short8 qf[4];
    {
        size_t base = ((size_t)(b * Sc + qt * 64 + w * 16 + lrow)) * Dc + h * HDc;
#pragma unroll
        for (int kk = 0; kk < 4; ++kk)
            qf[kk] = *(const short8*)&Q[base + kk * 32 + lhi * 8];
    }
    f32x4 accv[8];
#pragma unroll
    for (int n = 0; n < 8; ++n) accv[n] = (f32x4){0.f, 0.f, 0.f, 0.f};
    float mrun[4] = {-__builtin_inff(), -__builtin_inff(),
                     -__builtin_inff(), -__builtin_inff()};
    float lrun[4] = {0.f, 0.f, 0.f, 0.f};
    const float SCL = 0.08838834764831845f * 1.4426950408889634f;  // 1/sqrt(HD)*log2e

    for (int t = 0; t <= qt; ++t) {
        __syncthreads();
#pragma unroll
        for (int i = 0; i < 4; ++i) {
            int s = i * 256 + tid;
            {   // K tile: 64 rows x 128, 16 slots/row
                int row = s >> 4, c = s & 15;
                int cg = (c ^ (row & 7)) * 8;
                g2lds16(Kb + ((size_t)(b * Sc + t * 64 + row)) * Dc + h * HDc + cg,
                        &Ks[(size_t)(i * 256 + (w << 6)) * 8]);
            }
            {   // V tile: 128 rows (d) x 64 (kpos), 8 slots/row
                int row = s >> 3, c = s & 7;
                int cg = (c ^ (row & 7)) * 8;
                g2lds16(Vt + ((size_t)b * Dc + h * HDc + row) * Sc + t * 64 + cg,
                        &Vs[(size_t)(i * 256 + (w << 6)) * 8]);
            }
        }
        __syncthreads();

        f32x4 sc[4];
#pragma unroll
        for (int j = 0; j < 4; ++j) {
            f32x4 s4 = (f32x4){0.f, 0.f, 0.f, 0.f};
#pragma unroll
            for (int kk = 0; kk < 4; ++kk) {
                int row = j * 16 + lrow;
                short8 kf = *(const short8*)&Ks[row * 128 + (((kk * 4 + lhi) ^ (row & 7)) << 3)];
                s4 = __builtin_amdgcn_mfma_f32_16x16x32_bf16(qf[kk], kf, s4, 0, 0, 0);
            }
            sc[j] = s4;
        }
        const int kcol = t * 64 + lrow;
        const int qrow0 = qt * 64 + w * 16 + lhi * 4;
#pragma unroll
        for (int j = 0; j < 4; ++j)
#pragma unroll
            for (int r = 0; r < 4; ++r) {
                float v = sc[j][r] * SCL;
                sc[j][r] = (kcol + j * 16 > qrow0 + r) ? -1e30f : v;
            }
        float mt[4];
#pragma unroll
        for (int r = 0; r < 4; ++r)
            mt[r] = fmaxf(fmaxf(sc[0][r], sc[1][r]), fmaxf(sc[2][r], sc[3][r]));
#pragma unroll
        for (int d = 1; d < 16; d <<= 1)
#pragma unroll
            for (int r = 0; r < 4; ++r) mt[r] = fmaxf(mt[r], __shfl_xor(mt[r], d));

        float fs[4];
#pragma unroll
        for (int r = 0; r < 4; ++r) {
            float mnew = fmaxf(mrun[r], mt[r]);
            fs[r] = exp2f(mrun[r] - mnew);
            mrun[r] = mnew;
            float ps = 0.f;
            int q = lhi * 4 + r;
#pragma unroll
            for (int j = 0; j < 4; ++j) {
                float p = exp2f(sc[j][r] - mnew);
                ps += p;
                int kp = j * 16 + lrow;
                Ps[w * 1024 + q * 64 + (((kp >> 3) ^ (q & 7)) << 3) + (kp & 7)] = f2bf(p);
            }
#pragma unroll
            for (int d = 1; d < 16; d <<= 1) ps += __shfl_xor(ps, d);
            lrun[r] = lrun[r] * fs[r] + ps;
        }
#pragma unroll
        for (int n = 0; n < 8; ++n)
#pragma unroll
            for (int r = 0; r < 4; ++r) accv[n][r] *= fs[r];

#pragma unroll
        for (int kk = 0; kk < 2; ++kk) {
            short8 af = *(const short8*)&Ps[w * 1024 + lrow * 64 + (((kk * 4 + lhi) ^ (lrow & 7)) << 3)];
#pragma unroll
            for (int n = 0; n < 8; ++n) {
                int d = n * 16 + lrow;
                short8 vf = *(const short8*)&Vs[d * 64 + (((kk * 4 + lhi) ^ (d & 7)) << 3)];
                accv[n] = __builtin_amdgcn_mfma_f32_16x16x32_bf16(af, vf, accv[n], 0, 0, 0);
            }
        }
    }

#pragma unroll
    for (int n = 0; n < 8; ++n) {
        int d = n * 16 + lrow;
#pragma unroll
        for (int r = 0; r < 4; ++r) {
            int qg = qt * 64 + w * 16 + lhi * 4 + r;
            O[((size_t)(b * Sc + qg)) * Dc + h * HDc + d] = f2bf(accv[n][r] / lrun[r]);
        }
    }
}

// ------------------------------- launcher -----------------------------------
extern "C" void kernel_launch(void* const* d_in, const int* in_sizes, int n_in,
                              void* d_out, int out_size, void* d_ws, size_t ws_size,
                              hipStream_t stream) {
    const float* x  = (const float*)d_in[0];
    const float* wq = (const float*)d_in[1];
    const float* bq = (const float*)d_in[2];
    const float* wk = (const float*)d_in[3];
    const float* bk = (const float*)d_in[4];
    const float* wv = (const float*)d_in[5];
    const float* bv = (const float*)d_in[6];
    const float* wo = (const float*)d_in[7];
    const float* bo = (const float*)d_in[8];
    const float* rc = (const float*)d_in[9];
    const float* rs = (const float*)d_in[10];

    const size_t NE = (size_t)Mc * Dc;  // 8.4M elems (x / q / k / v / o each)
    const size_t NW = (size_t)Dc * Dc;  // 4.2M elems (one weight)

    unsigned short* xb = (unsigned short*)d_ws;  // x bf16; reused as attn out
    unsigned short* qb = xb + NE;
    unsigned short* kb = qb + NE;
    unsigned short* vt = kb + NE;                // V^T [B][D][S]
    unsigned short* wb = vt + NE;                // one converted weight

    const int ne8 = (int)(NE / 8), nw8 = (int)(NW / 8);
    dim3 gg(Nc / 128, Mc / 128), tb(256);

    cvt_f32_bf16<<<dim3(ne8 / 256), tb, 0, stream>>>(x, xb, ne8);

    cvt_f32_bf16<<<dim3(nw8 / 256), tb, 0, stream>>>(wq, wb, nw8);
    gemm_nt<0><<<gg, tb, 0, stream>>>(xb, wb, bq, rc, rs, qb);

    cvt_f32_bf16<<<dim3(nw8 / 256), tb, 0, stream>>>(wk, wb, nw8);
    gemm_nt<1><<<gg, tb, 0, stream>>>(xb, wb, bk, rc, rs, kb);

    cvt_f32_bf16<<<dim3(nw8 / 256), tb, 0, stream>>>(wv, wb, nw8);
    gemm_nt<2><<<gg, tb, 0, stream>>>(xb, wb, bv, rc, rs, vt);

    attn_fwd<<<dim3(Sc / 64, Bc * Hc), tb, 0, stream>>>(qb, kb, vt, xb);

    cvt_f32_bf16<<<dim3(nw8 / 256), tb, 0, stream>>>(wo, wb, nw8);
    gemm_nt<3><<<gg, tb, 0, stream>>>(xb, wb, bo, rc, rs, d_out);
}

// Round 2
// 300.683 us; speedup vs baseline: 1.3051x; 1.3051x over previous
//
#include <hip/hip_runtime.h>

// ---------------------------------------------------------------------------
// CasualMultiQueryAttention: x->(Q,K,V) proj + RoPE, causal flash attention,
// output projection. B=2,S=2048,D=2048,H=16,HD=128. bf16 MFMA compute.
// R2: attention rewritten to swapped-QK^T 32x32 MFMA structure (m214-style):
//     lane-local softmax, cvt_pk+permlane32_swap P redistribution, paired
//     q-tiles for causal load balance, 2-phase double-buffered staging.
// ---------------------------------------------------------------------------

typedef __attribute__((ext_vector_type(8))) short short8;
typedef __attribute__((ext_vector_type(4))) float f32x4;
typedef __attribute__((ext_vector_type(16))) float f32x16;
typedef __attribute__((ext_vector_type(4))) unsigned short u16x4;
typedef __attribute__((ext_vector_type(8))) unsigned short u16x8;

constexpr int Bc = 2, Sc = 2048, Dc = 2048, Hc = 16, HDc = 128;
constexpr int Mc = Bc * Sc;            // 4096 rows
constexpr int Nc = Dc, Kc = Dc;        // 2048

__device__ __forceinline__ unsigned short f2bf(float f) {
    union { float f; unsigned u; } x; x.f = f;
    unsigned r = x.u + 0x7FFFu + ((x.u >> 16) & 1u);   // RNE
    return (unsigned short)(r >> 16);
}
__device__ __forceinline__ float bf2f(unsigned short u) {
    union { float f; unsigned u; } x; x.u = (unsigned)u << 16; return x.f;
}

__device__ __forceinline__ void g2lds16(const void* g, void* l) {
    __builtin_amdgcn_global_load_lds(
        (const __attribute__((address_space(1))) void*)g,
        (__attribute__((address_space(3))) void*)l, 16, 0, 0);
}

// --------------------------- fp32 -> bf16 convert ---------------------------
__global__ __launch_bounds__(256) void cvt_f32_bf16(
    const float* __restrict__ in, unsigned short* __restrict__ out, int n8) {
    int i = blockIdx.x * 256 + threadIdx.x;
    if (i >= n8) return;
    f32x4 a = *((const f32x4*)in + (size_t)i * 2);
    f32x4 b = *((const f32x4*)in + (size_t)i * 2 + 1);
    u16x8 o;
    o[0] = f2bf(a[0]); o[1] = f2bf(a[1]); o[2] = f2bf(a[2]); o[3] = f2bf(a[3]);
    o[4] = f2bf(b[0]); o[5] = f2bf(b[1]); o[6] = f2bf(b[2]); o[7] = f2bf(b[3]);
    *((u16x8*)out + i) = o;
}

// --------------------------- NT GEMM, fused epilogues ------------------------
// C[M][N] = A[M][K] * W[N][K]^T + bias
// MODE 0: RoPE -> bf16 q    MODE 1: RoPE -> bf16 k
// MODE 2: -> bf16 V^T [B][D][S]   MODE 3: -> fp32 out
template <int MODE>
__global__ __launch_bounds__(256) void gemm_nt(
    const unsigned short* __restrict__ A, const unsigned short* __restrict__ W,
    const float* __restrict__ bias, const float* __restrict__ rc,
    const float* __restrict__ rs, void* __restrict__ outp) {
    __shared__ __align__(16) unsigned short As[128 * 64];
    __shared__ __align__(16) unsigned short Bs[128 * 64];
    const int tid = threadIdx.x;
    const int w = tid >> 6, l = tid & 63;
    const int wm = w >> 1, wn = w & 1;
    const int lrow = l & 15, lhi = l >> 4;
    const int m0 = blockIdx.y * 128, n0 = blockIdx.x * 128;

    f32x4 acc[4][4];
#pragma unroll
    for (int i = 0; i < 4; ++i)
#pragma unroll
        for (int j = 0; j < 4; ++j) acc[i][j] = (f32x4){0.f, 0.f, 0.f, 0.f};

    for (int k0 = 0; k0 < Kc; k0 += 64) {
        __syncthreads();
#pragma unroll
        for (int i = 0; i < 4; ++i) {
            int s = i * 256 + tid;
            int row = s >> 3, c = s & 7;
            int cg = (c ^ (row & 7)) * 8;      // pre-swizzled global source
            g2lds16(A + (size_t)(m0 + row) * Kc + k0 + cg,
                    &As[(size_t)(i * 256 + (w << 6)) * 8]);
            g2lds16(W + (size_t)(n0 + row) * Kc + k0 + cg,
                    &Bs[(size_t)(i * 256 + (w << 6)) * 8]);
        }
        __syncthreads();
#pragma unroll
        for (int kk = 0; kk < 2; ++kk) {
            short8 af[4], bf[4];
#pragma unroll
            for (int i = 0; i < 4; ++i) {
                int ra = wm * 64 + i * 16 + lrow;
                af[i] = *(const short8*)&As[ra * 64 + (((kk * 4 + lhi) ^ (ra & 7)) << 3)];
                int rb = wn * 64 + i * 16 + lrow;
                bf[i] = *(const short8*)&Bs[rb * 64 + (((kk * 4 + lhi) ^ (rb & 7)) << 3)];
            }
#pragma unroll
            for (int i = 0; i < 4; ++i)
#pragma unroll
                for (int j = 0; j < 4; ++j)
                    acc[i][j] = __builtin_amdgcn_mfma_f32_16x16x32_bf16(
                        af[i], bf[j], acc[i][j], 0, 0, 0);
        }
    }

#pragma unroll
    for (int i = 0; i < 4; ++i) {
#pragma unroll
        for (int j = 0; j < 4; ++j) {
            int gm0 = m0 + wm * 64 + i * 16 + lhi * 4;
            int gn  = n0 + wn * 64 + j * 16 + lrow;
            float bv = bias[gn];
            if (MODE == 0 || MODE == 1) {
                unsigned short* o = (unsigned short*)outp;
                int fi = (gn & (HDc - 1)) >> 1;
#pragma unroll
                for (int r = 0; r < 4; ++r) {
                    int gm = gm0 + r;
                    float v = acc[i][j][r] + bv;
                    float p = __shfl_xor(v, 1);          // partner column gn^1
                    int pos = gm & (Sc - 1);
                    float cz = rc[pos * (HDc / 2) + fi];
                    float sz = rs[pos * (HDc / 2) + fi];
                    float ov = (gn & 1) ? (p * sz + v * cz) : (v * cz - p * sz);
                    o[(size_t)gm * Nc + gn] = f2bf(ov);
                }
            } else if (MODE == 2) {
                unsigned short* o = (unsigned short*)outp;   // V^T [B][D][S]
                int b = gm0 >> 11, sb = gm0 & (Sc - 1);
                u16x4 pk;
#pragma unroll
                for (int r = 0; r < 4; ++r) pk[r] = f2bf(acc[i][j][r] + bv);
                *(u16x4*)&o[((size_t)b * Dc + gn) * Sc + sb] = pk;
            } else {
                float* o = (float*)outp;
#pragma unroll
                for (int r = 0; r < 4; ++r)
                    o[(size_t)(gm0 + r) * Nc + gn] = acc[i][j][r] + bv;
            }
        }
    }
}

// --------------------------- causal flash attention (v2) ---------------------
// 4 waves x 32 q-rows = QBLK 128. Paired q-tiles (qt, 15-qt) for equal work.
// Swapped QK^T: S^T = K.Q^T via mfma_32x32x16 -> lane owns one q-row.
// PV: O^T = V^T.P^T; P redistributed in-register via cvt_pk + permlane32_swap.
__global__ __launch_bounds__(256) void attn_fwd2(
    const unsigned short* __restrict__ Q, const unsigned short* __restrict__ Kb,
    const unsigned short* __restrict__ Vt, unsigned short* __restrict__ O) {
    __shared__ __align__(16) unsigned short Ks[2][64 * 128];
    __shared__ __align__(16) unsigned short Vs[2][128 * 64];
    const int tid = threadIdx.x;
    const int w = tid >> 6, l = tid & 63;
    const int ql = l & 31, H = l >> 5;
    const int pair = blockIdx.x;
    const int b = blockIdx.y >> 4, h = blockIdx.y & 15;
    const float SCL2 = 0.08838834764831845f * 1.4426950408889634f; // 1/sqrt(HD)*log2e

    const unsigned short* Kbase = Kb + ((size_t)b * Sc) * Dc + h * HDc;
    const unsigned short* Vbase = Vt + ((size_t)b * Dc + h * HDc) * Sc;

#define STAGE(tt, bb) {                                                        \
    const unsigned short* Kt = Kbase + (size_t)(tt) * 64 * Dc;                 \
    const unsigned short* Vp = Vbase + (tt) * 64;                              \
    _Pragma("unroll")                                                          \
    for (int i_ = 0; i_ < 4; ++i_) {                                           \
        int p_ = i_ * 256 + tid;                                               \
        int rK = p_ >> 4, sK = p_ & 15;                                        \
        g2lds16(Kt + (size_t)rK * Dc + ((sK ^ (rK & 15)) << 3),                \
                &Ks[bb][(i_ * 256 + (w << 6)) * 8]);                           \
        int rV = p_ >> 3, sV = p_ & 7;                                         \
        g2lds16(Vp + (size_t)rV * Sc + ((sV ^ (rV & 7)) << 3),                 \
                &Vs[bb][(i_ * 256 + (w << 6)) * 8]);                           \
    } }

#define PVSTEP(PC, HB, KS) {                                                   \
    int X0, X1, Y0, Y1;                                                        \
    asm("v_cvt_pk_bf16_f32 %0, %1, %2" : "=v"(X0) : "v"(PC[HB+0]), "v"(PC[HB+1])); \
    asm("v_cvt_pk_bf16_f32 %0, %1, %2" : "=v"(X1) : "v"(PC[HB+2]), "v"(PC[HB+3])); \
    asm("v_cvt_pk_bf16_f32 %0, %1, %2" : "=v"(Y0) : "v"(PC[HB+4]), "v"(PC[HB+5])); \
    asm("v_cvt_pk_bf16_f32 %0, %1, %2" : "=v"(Y1) : "v"(PC[HB+6]), "v"(PC[HB+7])); \
    asm("v_permlane32_swap_b32 %0, %1" : "+v"(X0), "+v"(Y0));                  \
    asm("v_permlane32_swap_b32 %0, %1" : "+v"(X1), "+v"(Y1));                  \
    union { int i[4]; short8 s; } pf_;                                         \
    pf_.i[0] = X0; pf_.i[1] = X1; pf_.i[2] = Y0; pf_.i[3] = Y1;                \
    _Pragma("unroll")                                                          \
    for (int dc_ = 0; dc_ < 4; ++dc_) {                                        \
        int rr = 32 * dc_ + ql;                                                \
        short8 vf = *(const short8*)&Vs[cur][rr * 64 + (((2*(KS)+H) ^ (rr & 7)) << 3)]; \
        accv[dc_] = __builtin_amdgcn_mfma_f32_32x32x16_bf16(vf, pf_.s, accv[dc_], 0, 0, 0); \
    } }

    for (int qi = 0; qi < 2; ++qi) {
        const int qt = qi ? (15 - pair) : pair;
        const int qb0 = qt * 128;
        const int qw0 = qb0 + w * 32;
        const int qg = qw0 + ql;

        // Q fragments (pre-scaled by 1/sqrt(HD)*log2e): B-frag, lane owns q=ql
        short8 qf[8];
        {
            const unsigned short* qp = Q + ((size_t)(b * Sc + qg)) * Dc + h * HDc;
#pragma unroll
            for (int dc = 0; dc < 8; ++dc) {
                u16x8 v = *(const u16x8*)(qp + dc * 16 + H * 8);
                u16x8 o;
#pragma unroll
                for (int j = 0; j < 8; ++j) o[j] = f2bf(bf2f(v[j]) * SCL2);
                qf[dc] = (short8)o;
            }
        }
        f32x16 accv[4];
#pragma unroll
        for (int i = 0; i < 4; ++i) accv[i] = (f32x16)(0.f);
        float mrun = -3.0e38f, lrun = 0.f;
        const int nt = 2 * qt + 2;

        STAGE(0, 0);
        __syncthreads();
        int cur = 0;
        for (int t = 0; t < nt; ++t) {
            if (t + 1 < nt) STAGE(t + 1, cur ^ 1);
            const int kb0 = t * 64;
            if (kb0 <= qw0 + 31) {                       // wave has unmasked work
                // ---- QK^T (swapped): S^T[k][q], two 32-k subtiles ----
                f32x16 a0 = (f32x16)(0.f), a1 = (f32x16)(0.f);
#pragma unroll
                for (int dc = 0; dc < 8; ++dc) {
                    int r0 = ql, r1 = 32 + ql, sl = dc * 2 + H;
                    short8 k0 = *(const short8*)&Ks[cur][r0 * 128 + ((sl ^ (r0 & 15)) << 3)];
                    short8 k1 = *(const short8*)&Ks[cur][r1 * 128 + ((sl ^ (r1 & 15)) << 3)];
                    a0 = __builtin_amdgcn_mfma_f32_32x32x16_bf16(k0, qf[dc], a0, 0, 0, 0);
                    a1 = __builtin_amdgcn_mfma_f32_32x32x16_bf16(k1, qf[dc], a1, 0, 0, 0);
                }
                if (t >= 2 * qt) {                       // boundary tile: causal mask
#pragma unroll
                    for (int r = 0; r < 16; ++r) {
                        int kl = (r & 3) + 8 * (r >> 2) + 4 * H;
                        if (kb0 + kl > qg)      a0[r] = -3.0e38f;
                        if (kb0 + 32 + kl > qg) a1[r] = -3.0e38f;
                    }
                }
                // ---- online softmax (lane-local: one q-row per lane) ----
                float pm = -3.0e38f;
#pragma unroll
                for (int r = 0; r < 16; ++r) pm = fmaxf(pm, a0[r]);
#pragma unroll
                for (int r = 0; r < 16; ++r) pm = fmaxf(pm, a1[r]);
                pm = fmaxf(pm, __shfl_xor(pm, 32));
                float mnew = fmaxf(mrun, pm);
                float fs = exp2f(mrun - mnew);
                float p0[16], p1[16], ps = 0.f;
#pragma unroll
                for (int r = 0; r < 16; ++r) { p0[r] = exp2f(a0[r] - mnew); ps += p0[r]; }
#pragma unroll
                for (int r = 0; r < 16; ++r) { p1[r] = exp2f(a1[r] - mnew); ps += p1[r]; }
                ps += __shfl_xor(ps, 32);
                mrun = mnew;
                lrun = lrun * fs + ps;
#pragma unroll
                for (int dc = 0; dc < 4; ++dc)
#pragma unroll
                    for (int r = 0; r < 16; ++r) accv[dc][r] *= fs;
                // ---- PV: O^T += V^T . P^T  (4 k-steps of 16) ----
                PVSTEP(p0, 0, 0); PVSTEP(p0, 8, 1);
                PVSTEP(p1, 0, 2); PVSTEP(p1, 8, 3);
            }
            __syncthreads();
            cur ^= 1;
        }
        // ---- epilogue: O^T -> O, /l, bf16 ----
        float inv = 1.f / lrun;
        unsigned short* Op = O + ((size_t)(b * Sc + qg)) * Dc + h * HDc;
#pragma unroll
        for (int dc = 0; dc < 4; ++dc)
#pragma unroll
            for (int rg = 0; rg < 4; ++rg) {
                int d0 = 32 * dc + 8 * rg + 4 * H;
                u16x4 pk;
#pragma unroll
                for (int j = 0; j < 4; ++j) pk[j] = f2bf(accv[dc][rg * 4 + j] * inv);
                *(u16x4*)(Op + d0) = pk;
            }
    }
#undef STAGE
#undef PVSTEP
}

// ------------------------------- launcher -----------------------------------
extern "C" void kernel_launch(void* const* d_in, const int* in_sizes, int n_in,
                              void* d_out, int out_size, void* d_ws, size_t ws_size,
                              hipStream_t stream) {
    const float* x  = (const float*)d_in[0];
    const float* wq = (const float*)d_in[1];
    const float* bq = (const float*)d_in[2];
    const float* wk = (const float*)d_in[3];
    const float* bk = (const float*)d_in[4];
    const float* wv = (const float*)d_in[5];
    const float* bv = (const float*)d_in[6];
    const float* wo = (const float*)d_in[7];
    const float* bo = (const float*)d_in[8];
    const float* rc = (const float*)d_in[9];
    const float* rs = (const float*)d_in[10];

    const size_t NE = (size_t)Mc * Dc;  // 8.4M elems (x / q / k / v / o each)
    const size_t NW = (size_t)Dc * Dc;  // 4.2M elems (one weight)

    unsigned short* xb = (unsigned short*)d_ws;  // x bf16; reused as attn out
    unsigned short* qb = xb + NE;
    unsigned short* kb = qb + NE;
    unsigned short* vt = kb + NE;                // V^T [B][D][S]
    unsigned short* wb = vt + NE;                // one converted weight

    const int ne8 = (int)(NE / 8), nw8 = (int)(NW / 8);
    dim3 gg(Nc / 128, Mc / 128), tb(256);

    cvt_f32_bf16<<<dim3(ne8 / 256), tb, 0, stream>>>(x, xb, ne8);

    cvt_f32_bf16<<<dim3(nw8 / 256), tb, 0, stream>>>(wq, wb, nw8);
    gemm_nt<0><<<gg, tb, 0, stream>>>(xb, wb, bq, rc, rs, qb);

    cvt_f32_bf16<<<dim3(nw8 / 256), tb, 0, stream>>>(wk, wb, nw8);
    gemm_nt<1><<<gg, tb, 0, stream>>>(xb, wb, bk, rc, rs, kb);

    cvt_f32_bf16<<<dim3(nw8 / 256), tb, 0, stream>>>(wv, wb, nw8);
    gemm_nt<2><<<gg, tb, 0, stream>>>(xb, wb, bv, rc, rs, vt);

    attn_fwd2<<<dim3(8, Bc * Hc), tb, 0, stream>>>(qb, kb, vt, xb);

    cvt_f32_bf16<<<dim3(nw8 / 256), tb, 0, stream>>>(wo, wb, nw8);
    gemm_nt<3><<<gg, tb, 0, stream>>>(xb, wb, bo, rc, rs, d_out);
}

// Round 3
// 281.807 us; speedup vs baseline: 1.3926x; 1.0670x over previous
//
#include <hip/hip_runtime.h>

// ---------------------------------------------------------------------------
// CasualMultiQueryAttention: x->(Q,K,V) proj + RoPE, causal flash attention,
// output projection. B=2,S=2048,D=2048,H=16,HD=128. bf16 MFMA compute.
// R3: attention gets (a) bh-major grid so same-(b,h) blocks share an XCD L2,
//     (b) depth-3 prefetch ring with counted vmcnt + raw s_barrier (T3/T4),
//     (c) defer-max rescale skip (T13), (d) setprio around MFMA (T5).
//     Q pre-scaled in gemm<0> epilogue. Converts batched into one launch.
// ---------------------------------------------------------------------------

typedef __attribute__((ext_vector_type(8))) short short8;
typedef __attribute__((ext_vector_type(4))) float f32x4;
typedef __attribute__((ext_vector_type(16))) float f32x16;
typedef __attribute__((ext_vector_type(4))) unsigned short u16x4;
typedef __attribute__((ext_vector_type(8))) unsigned short u16x8;

constexpr int Bc = 2, Sc = 2048, Dc = 2048, Hc = 16, HDc = 128;
constexpr int Mc = Bc * Sc;            // 4096 rows
constexpr int Nc = Dc, Kc = Dc;        // 2048
constexpr float QSCL = 0.08838834764831845f * 1.4426950408889634f; // 1/sqrt(HD)*log2e

__device__ __forceinline__ unsigned short f2bf(float f) {
    union { float f; unsigned u; } x; x.f = f;
    unsigned r = x.u + 0x7FFFu + ((x.u >> 16) & 1u);   // RNE
    return (unsigned short)(r >> 16);
}

__device__ __forceinline__ void g2lds16(const void* g, void* l) {
    __builtin_amdgcn_global_load_lds(
        (const __attribute__((address_space(1))) void*)g,
        (__attribute__((address_space(3))) void*)l, 16, 0, 0);
}

// --------------------------- fp32 -> bf16 convert ---------------------------
__device__ __forceinline__ void cvt_body(const float* __restrict__ in,
                                         unsigned short* __restrict__ out, int i) {
    f32x4 a = *((const f32x4*)in + (size_t)i * 2);
    f32x4 b = *((const f32x4*)in + (size_t)i * 2 + 1);
    u16x8 o;
    o[0] = f2bf(a[0]); o[1] = f2bf(a[1]); o[2] = f2bf(a[2]); o[3] = f2bf(a[3]);
    o[4] = f2bf(b[0]); o[5] = f2bf(b[1]); o[6] = f2bf(b[2]); o[7] = f2bf(b[3]);
    *((u16x8*)out + i) = o;
}

__global__ __launch_bounds__(256) void cvt_f32_bf16(
    const float* __restrict__ in, unsigned short* __restrict__ out, int n8) {
    int i = blockIdx.x * 256 + threadIdx.x;
    if (i >= n8) return;
    cvt_body(in, out, i);
}

// x + 4 weights in one launch. blockIdx.y selects tensor.
__global__ __launch_bounds__(256) void cvt_batch(
    const float* __restrict__ x,  unsigned short* __restrict__ xo,
    const float* __restrict__ w0, unsigned short* __restrict__ o0,
    const float* __restrict__ w1, unsigned short* __restrict__ o1,
    const float* __restrict__ w2, unsigned short* __restrict__ o2,
    const float* __restrict__ w3, unsigned short* __restrict__ o3) {
    const int which = blockIdx.y;
    const float* in; unsigned short* out; int n8;
    if (which == 0)      { in = x;  out = xo; n8 = (Mc * Dc) / 8; }
    else if (which == 1) { in = w0; out = o0; n8 = (Dc * Dc) / 8; }
    else if (which == 2) { in = w1; out = o1; n8 = (Dc * Dc) / 8; }
    else if (which == 3) { in = w2; out = o2; n8 = (Dc * Dc) / 8; }
    else                 { in = w3; out = o3; n8 = (Dc * Dc) / 8; }
    int i = blockIdx.x * 256 + threadIdx.x;
    if (i >= n8) return;
    cvt_body(in, out, i);
}

// --------------------------- NT GEMM, fused epilogues ------------------------
// C[M][N] = A[M][K] * W[N][K]^T + bias
// MODE 0: RoPE -> bf16 q (pre-scaled by QSCL)   MODE 1: RoPE -> bf16 k
// MODE 2: -> bf16 V^T [B][D][S]                 MODE 3: -> fp32 out
template <int MODE>
__global__ __launch_bounds__(256) void gemm_nt(
    const unsigned short* __restrict__ A, const unsigned short* __restrict__ W,
    const float* __restrict__ bias, const float* __restrict__ rc,
    const float* __restrict__ rs, void* __restrict__ outp) {
    __shared__ __align__(16) unsigned short As[128 * 64];
    __shared__ __align__(16) unsigned short Bs[128 * 64];
    const int tid = threadIdx.x;
    const int w = tid >> 6, l = tid & 63;
    const int wm = w >> 1, wn = w & 1;
    const int lrow = l & 15, lhi = l >> 4;
    const int m0 = blockIdx.y * 128, n0 = blockIdx.x * 128;

    f32x4 acc[4][4];
#pragma unroll
    for (int i = 0; i < 4; ++i)
#pragma unroll
        for (int j = 0; j < 4; ++j) acc[i][j] = (f32x4){0.f, 0.f, 0.f, 0.f};

    for (int k0 = 0; k0 < Kc; k0 += 64) {
        __syncthreads();
#pragma unroll
        for (int i = 0; i < 4; ++i) {
            int s = i * 256 + tid;
            int row = s >> 3, c = s & 7;
            int cg = (c ^ (row & 7)) * 8;      // pre-swizzled global source
            g2lds16(A + (size_t)(m0 + row) * Kc + k0 + cg,
                    &As[(size_t)(i * 256 + (w << 6)) * 8]);
            g2lds16(W + (size_t)(n0 + row) * Kc + k0 + cg,
                    &Bs[(size_t)(i * 256 + (w << 6)) * 8]);
        }
        __syncthreads();
#pragma unroll
        for (int kk = 0; kk < 2; ++kk) {
            short8 af[4], bf[4];
#pragma unroll
            for (int i = 0; i < 4; ++i) {
                int ra = wm * 64 + i * 16 + lrow;
                af[i] = *(const short8*)&As[ra * 64 + (((kk * 4 + lhi) ^ (ra & 7)) << 3)];
                int rb = wn * 64 + i * 16 + lrow;
                bf[i] = *(const short8*)&Bs[rb * 64 + (((kk * 4 + lhi) ^ (rb & 7)) << 3)];
            }
#pragma unroll
            for (int i = 0; i < 4; ++i)
#pragma unroll
                for (int j = 0; j < 4; ++j)
                    acc[i][j] = __builtin_amdgcn_mfma_f32_16x16x32_bf16(
                        af[i], bf[j], acc[i][j], 0, 0, 0);
        }
    }

#pragma unroll
    for (int i = 0; i < 4; ++i) {
#pragma unroll
        for (int j = 0; j < 4; ++j) {
            int gm0 = m0 + wm * 64 + i * 16 + lhi * 4;
            int gn  = n0 + wn * 64 + j * 16 + lrow;
            float bv = bias[gn];
            if (MODE == 0 || MODE == 1) {
                unsigned short* o = (unsigned short*)outp;
                int fi = (gn & (HDc - 1)) >> 1;
#pragma unroll
                for (int r = 0; r < 4; ++r) {
                    int gm = gm0 + r;
                    float v = acc[i][j][r] + bv;
                    float p = __shfl_xor(v, 1);          // partner column gn^1
                    int pos = gm & (Sc - 1);
                    float cz = rc[pos * (HDc / 2) + fi];
                    float sz = rs[pos * (HDc / 2) + fi];
                    float ov = (gn & 1) ? (p * sz + v * cz) : (v * cz - p * sz);
                    if (MODE == 0) ov *= QSCL;           // fold attn scale into q
                    o[(size_t)gm * Nc + gn] = f2bf(ov);
                }
            } else if (MODE == 2) {
                unsigned short* o = (unsigned short*)outp;   // V^T [B][D][S]
                int b = gm0 >> 11, sb = gm0 & (Sc - 1);
                u16x4 pk;
#pragma unroll
                for (int r = 0; r < 4; ++r) pk[r] = f2bf(acc[i][j][r] + bv);
                *(u16x4*)&o[((size_t)b * Dc + gn) * Sc + sb] = pk;
            } else {
                float* o = (float*)outp;
#pragma unroll
                for (int r = 0; r < 4; ++r)
                    o[(size_t)(gm0 + r) * Nc + gn] = acc[i][j][r] + bv;
            }
        }
    }
}

// --------------------------- causal flash attention (v3) ---------------------
// grid (32 bh, 8 pair): same-bh blocks land on one XCD (id = bh + 32*pair).
// 4 waves x 32 q-rows; paired q-tiles (qt, 15-qt); swapped QK^T 32x32 MFMA;
// depth-3 LDS ring, counted vmcnt, raw barriers; defer-max rescale.
__global__ __launch_bounds__(256) void attn_fwd3(
    const unsigned short* __restrict__ Q, const unsigned short* __restrict__ Kb,
    const unsigned short* __restrict__ Vt, unsigned short* __restrict__ O) {
    __shared__ __align__(16) unsigned short Ks[3][64 * 128];
    __shared__ __align__(16) unsigned short Vs[3][128 * 64];
    const int tid = threadIdx.x;
    const int w = tid >> 6, l = tid & 63;
    const int ql = l & 31, Hh = l >> 5;
    const int bh = blockIdx.x;                 // 0..31
    const int pair = blockIdx.y;               // 0..7
    const int b = bh >> 4, h = bh & 15;

    const unsigned short* Kbase = Kb + ((size_t)b * Sc) * Dc + h * HDc;
    const unsigned short* Vbase = Vt + ((size_t)b * Dc + h * HDc) * Sc;

#define STAGE(tt, kd, vd) {                                                    \
    const unsigned short* Kt = Kbase + (size_t)(tt) * 64 * Dc;                 \
    const unsigned short* Vp = Vbase + (tt) * 64;                              \
    _Pragma("unroll")                                                          \
    for (int i_ = 0; i_ < 4; ++i_) {                                           \
        int p_ = i_ * 256 + tid;                                               \
        int rK = p_ >> 4, sK = p_ & 15;                                        \
        g2lds16(Kt + (size_t)rK * Dc + ((sK ^ (rK & 15)) << 3),                \
                (kd) + (i_ * 256 + (w << 6)) * 8);                             \
        int rV = p_ >> 3, sV = p_ & 7;                                         \
        g2lds16(Vp + (size_t)rV * Sc + ((sV ^ (rV & 7)) << 3),                 \
                (vd) + (i_ * 256 + (w << 6)) * 8);                             \
    } }

#define PVSTEP(PC, HB, KS) {                                                   \
    int X0, X1, Y0, Y1;                                                        \
    asm("v_cvt_pk_bf16_f32 %0, %1, %2" : "=v"(X0) : "v"(PC[HB+0]), "v"(PC[HB+1])); \
    asm("v_cvt_pk_bf16_f32 %0, %1, %2" : "=v"(X1) : "v"(PC[HB+2]), "v"(PC[HB+3])); \
    asm("v_cvt_pk_bf16_f32 %0, %1, %2" : "=v"(Y0) : "v"(PC[HB+4]), "v"(PC[HB+5])); \
    asm("v_cvt_pk_bf16_f32 %0, %1, %2" : "=v"(Y1) : "v"(PC[HB+6]), "v"(PC[HB+7])); \
    asm("v_permlane32_swap_b32 %0, %1" : "+v"(X0), "+v"(Y0));                  \
    asm("v_permlane32_swap_b32 %0, %1" : "+v"(X1), "+v"(Y1));                  \
    union { int i[4]; short8 s; } pf_;                                         \
    pf_.i[0] = X0; pf_.i[1] = X1; pf_.i[2] = Y0; pf_.i[3] = Y1;                \
    _Pragma("unroll")                                                          \
    for (int dc_ = 0; dc_ < 4; ++dc_) {                                        \
        int rr = 32 * dc_ + ql;                                                \
        short8 vf = *(const short8*)&Vbuf[rr * 64 + (((2*(KS)+Hh) ^ (rr & 7)) << 3)]; \
        accv[dc_] = __builtin_amdgcn_mfma_f32_32x32x16_bf16(vf, pf_.s, accv[dc_], 0, 0, 0); \
    } }

    for (int qi = 0; qi < 2; ++qi) {
        const int qt = qi ? (15 - pair) : pair;
        const int qw0 = qt * 128 + w * 32;
        const int qg = qw0 + ql;

        // Q fragments (already scaled by QSCL in gemm<0>)
        short8 qf[8];
        {
            const unsigned short* qp = Q + ((size_t)(b * Sc + qg)) * Dc + h * HDc;
#pragma unroll
            for (int dc = 0; dc < 8; ++dc)
                qf[dc] = *(const short8*)(qp + dc * 16 + Hh * 8);
        }
        f32x16 accv[4];
#pragma unroll
        for (int i = 0; i < 4; ++i) accv[i] = (f32x16)(0.f);
        float mrun = -3.0e38f, lrun = 0.f;
        const int nt = 2 * qt + 2;

        STAGE(0, Ks[0], Vs[0]);
        STAGE(1, Ks[1], Vs[1]);
        for (int t = 0; t < nt; ++t) {
            if (t + 2 < nt) {
                STAGE(t + 2, Ks[(t + 2) % 3], Vs[(t + 2) % 3]);
                asm volatile("s_waitcnt vmcnt(16)" ::: "memory");   // tile t landed
            } else if (t + 1 < nt) {
                asm volatile("s_waitcnt vmcnt(8)" ::: "memory");
            } else {
                asm volatile("s_waitcnt vmcnt(0)" ::: "memory");
            }
            __builtin_amdgcn_s_barrier();      // all waves' tile-t loads visible

            const unsigned short* Kbuf = Ks[t % 3];
            const unsigned short* Vbuf = Vs[t % 3];
            const int kb0 = t * 64;
            if (kb0 <= qw0 + 31) {                       // wave has unmasked work
                // ---- QK^T (swapped): S^T[k][q], two 32-k subtiles ----
                f32x16 a0 = (f32x16)(0.f), a1 = (f32x16)(0.f);
                __builtin_amdgcn_s_setprio(1);
#pragma unroll
                for (int dc = 0; dc < 8; ++dc) {
                    int r0 = ql, r1 = 32 + ql, sl = dc * 2 + Hh;
                    short8 k0 = *(const short8*)&Kbuf[r0 * 128 + ((sl ^ (r0 & 15)) << 3)];
                    short8 k1 = *(const short8*)&Kbuf[r1 * 128 + ((sl ^ (r1 & 15)) << 3)];
                    a0 = __builtin_amdgcn_mfma_f32_32x32x16_bf16(k0, qf[dc], a0, 0, 0, 0);
                    a1 = __builtin_amdgcn_mfma_f32_32x32x16_bf16(k1, qf[dc], a1, 0, 0, 0);
                }
                __builtin_amdgcn_s_setprio(0);
                if (t >= 2 * qt) {                       // boundary tile: causal mask
#pragma unroll
                    for (int r = 0; r < 16; ++r) {
                        int kl = (r & 3) + 8 * (r >> 2) + 4 * Hh;
                        if (kb0 + kl > qg)      a0[r] = -3.0e38f;
                        if (kb0 + 32 + kl > qg) a1[r] = -3.0e38f;
                    }
                }
                // ---- online softmax, lane-local; defer-max (T13, THR=8) ----
                float pm = -3.0e38f;
#pragma unroll
                for (int r = 0; r < 16; ++r) pm = fmaxf(pm, a0[r]);
#pragma unroll
                for (int r = 0; r < 16; ++r) pm = fmaxf(pm, a1[r]);
                pm = fmaxf(pm, __shfl_xor(pm, 32));
                if (!__all(pm - mrun <= 8.0f)) {
                    float mnew = fmaxf(mrun, pm);
                    float fs = exp2f(mrun - mnew);
                    mrun = mnew;
                    lrun *= fs;
#pragma unroll
                    for (int dc = 0; dc < 4; ++dc)
#pragma unroll
                        for (int r = 0; r < 16; ++r) accv[dc][r] *= fs;
                }
                float p0[16], p1[16], ps = 0.f;
#pragma unroll
                for (int r = 0; r < 16; ++r) { p0[r] = exp2f(a0[r] - mrun); ps += p0[r]; }
#pragma unroll
                for (int r = 0; r < 16; ++r) { p1[r] = exp2f(a1[r] - mrun); ps += p1[r]; }
                ps += __shfl_xor(ps, 32);
                lrun += ps;
                // ---- PV: O^T += V^T . P^T  (4 k-steps of 16) ----
                __builtin_amdgcn_s_setprio(1);
                PVSTEP(p0, 0, 0); PVSTEP(p0, 8, 1);
                PVSTEP(p1, 0, 2); PVSTEP(p1, 8, 3);
                __builtin_amdgcn_s_setprio(0);
            }
            __builtin_amdgcn_s_barrier();      // done reading buf t%3
        }
        // ---- epilogue: O^T -> O, /l, bf16 ----
        float inv = 1.f / lrun;
        unsigned short* Op = O + ((size_t)(b * Sc + qg)) * Dc + h * HDc;
#pragma unroll
        for (int dc = 0; dc < 4; ++dc)
#pragma unroll
            for (int rg = 0; rg < 4; ++rg) {
                int d0 = 32 * dc + 8 * rg + 4 * Hh;
                u16x4 pk;
#pragma unroll
                for (int j = 0; j < 4; ++j) pk[j] = f2bf(accv[dc][rg * 4 + j] * inv);
                *(u16x4*)(Op + d0) = pk;
            }
    }
#undef STAGE
#undef PVSTEP
}

// ------------------------------- launcher -----------------------------------
extern "C" void kernel_launch(void* const* d_in, const int* in_sizes, int n_in,
                              void* d_out, int out_size, void* d_ws, size_t ws_size,
                              hipStream_t stream) {
    const float* x  = (const float*)d_in[0];
    const float* wq = (const float*)d_in[1];
    const float* bq = (const float*)d_in[2];
    const float* wk = (const float*)d_in[3];
    const float* bk = (const float*)d_in[4];
    const float* wv = (const float*)d_in[5];
    const float* bv = (const float*)d_in[6];
    const float* wo = (const float*)d_in[7];
    const float* bo = (const float*)d_in[8];
    const float* rc = (const float*)d_in[9];
    const float* rs = (const float*)d_in[10];

    const size_t NE = (size_t)Mc * Dc;  // 8.4M elems (x / q / k / v / o each)
    const size_t NW = (size_t)Dc * Dc;  // 4.2M elems (one weight)

    unsigned short* xb = (unsigned short*)d_ws;  // x bf16; reused as attn out
    unsigned short* qb = xb + NE;
    unsigned short* kb = qb + NE;
    unsigned short* vt = kb + NE;                // V^T [B][D][S]
    unsigned short* wb = vt + NE;                // weight buffer(s)

    const int ne8 = (int)(NE / 8), nw8 = (int)(NW / 8);
    dim3 gg(Nc / 128, Mc / 128), tb(256);
    const bool big_ws = ws_size >= (4 * NE + 4 * NW) * sizeof(unsigned short);

    if (big_ws) {
        unsigned short* wqb = wb;
        unsigned short* wkb = wb + NW;
        unsigned short* wvb = wb + 2 * NW;
        unsigned short* wob = wb + 3 * NW;
        cvt_batch<<<dim3(ne8 / 256, 5), tb, 0, stream>>>(
            x, xb, wq, wqb, wk, wkb, wv, wvb, wo, wob);
        gemm_nt<0><<<gg, tb, 0, stream>>>(xb, wqb, bq, rc, rs, qb);
        gemm_nt<1><<<gg, tb, 0, stream>>>(xb, wkb, bk, rc, rs, kb);
        gemm_nt<2><<<gg, tb, 0, stream>>>(xb, wvb, bv, rc, rs, vt);
        attn_fwd3<<<dim3(Bc * Hc, 8), tb, 0, stream>>>(qb, kb, vt, xb);
        gemm_nt<3><<<gg, tb, 0, stream>>>(xb, wob, bo, rc, rs, d_out);
    } else {
        cvt_f32_bf16<<<dim3(ne8 / 256), tb, 0, stream>>>(x, xb, ne8);
        cvt_f32_bf16<<<dim3(nw8 / 256), tb, 0, stream>>>(wq, wb, nw8);
        gemm_nt<0><<<gg, tb, 0, stream>>>(xb, wb, bq, rc, rs, qb);
        cvt_f32_bf16<<<dim3(nw8 / 256), tb, 0, stream>>>(wk, wb, nw8);
        gemm_nt<1><<<gg, tb, 0, stream>>>(xb, wb, bk, rc, rs, kb);
        cvt_f32_bf16<<<dim3(nw8 / 256), tb, 0, stream>>>(wv, wb, nw8);
        gemm_nt<2><<<gg, tb, 0, stream>>>(xb, wb, bv, rc, rs, vt);
        attn_fwd3<<<dim3(Bc * Hc, 8), tb, 0, stream>>>(qb, kb, vt, xb);
        cvt_f32_bf16<<<dim3(nw8 / 256), tb, 0, stream>>>(wo, wb, nw8);
        gemm_nt<3><<<gg, tb, 0, stream>>>(xb, wb, bo, rc, rs, d_out);
    }
}

// Round 5
// 272.107 us; speedup vs baseline: 1.4422x; 1.0356x over previous
//
#include <hip/hip_runtime.h>

// ---------------------------------------------------------------------------
// CasualMultiQueryAttention: x->(Q,K,V) proj + RoPE, causal flash attention,
// output projection. B=2,S=2048,D=2048,H=16,HD=128. bf16 MFMA compute.
// R5: R4 structure (512 one-qtile blocks, qt<->15-qt co-residency pairing,
//     ring-2 LDS + counted vmcnt, launch_bounds(256,2), tree reductions)
//     with cross-half reductions reverted to proven __shfl_xor(.,32)
//     (R4's permlane-based xhalf_* was the only unproven primitive and the
//     prime suspect for the absmax=3.26 failure).
// ---------------------------------------------------------------------------

typedef __attribute__((ext_vector_type(8))) short short8;
typedef __attribute__((ext_vector_type(4))) float f32x4;
typedef __attribute__((ext_vector_type(16))) float f32x16;
typedef __attribute__((ext_vector_type(4))) unsigned short u16x4;
typedef __attribute__((ext_vector_type(8))) unsigned short u16x8;

constexpr int Bc = 2, Sc = 2048, Dc = 2048, Hc = 16, HDc = 128;
constexpr int Mc = Bc * Sc;            // 4096 rows
constexpr int Nc = Dc, Kc = Dc;        // 2048
constexpr float QSCL = 0.08838834764831845f * 1.4426950408889634f; // 1/sqrt(HD)*log2e

__device__ __forceinline__ unsigned short f2bf(float f) {
    union { float f; unsigned u; } x; x.f = f;
    unsigned r = x.u + 0x7FFFu + ((x.u >> 16) & 1u);   // RNE
    return (unsigned short)(r >> 16);
}

__device__ __forceinline__ void g2lds16(const void* g, void* l) {
    __builtin_amdgcn_global_load_lds(
        (const __attribute__((address_space(1))) void*)g,
        (__attribute__((address_space(3))) void*)l, 16, 0, 0);
}

// --------------------------- fp32 -> bf16 convert ---------------------------
__device__ __forceinline__ void cvt_body(const float* __restrict__ in,
                                         unsigned short* __restrict__ out, int i) {
    f32x4 a = *((const f32x4*)in + (size_t)i * 2);
    f32x4 b = *((const f32x4*)in + (size_t)i * 2 + 1);
    u16x8 o;
    o[0] = f2bf(a[0]); o[1] = f2bf(a[1]); o[2] = f2bf(a[2]); o[3] = f2bf(a[3]);
    o[4] = f2bf(b[0]); o[5] = f2bf(b[1]); o[6] = f2bf(b[2]); o[7] = f2bf(b[3]);
    *((u16x8*)out + i) = o;
}

__global__ __launch_bounds__(256) void cvt_f32_bf16(
    const float* __restrict__ in, unsigned short* __restrict__ out, int n8) {
    int i = blockIdx.x * 256 + threadIdx.x;
    if (i >= n8) return;
    cvt_body(in, out, i);
}

// x + 4 weights in one launch. blockIdx.y selects tensor.
__global__ __launch_bounds__(256) void cvt_batch(
    const float* __restrict__ x,  unsigned short* __restrict__ xo,
    const float* __restrict__ w0, unsigned short* __restrict__ o0,
    const float* __restrict__ w1, unsigned short* __restrict__ o1,
    const float* __restrict__ w2, unsigned short* __restrict__ o2,
    const float* __restrict__ w3, unsigned short* __restrict__ o3) {
    const int which = blockIdx.y;
    const float* in; unsigned short* out; int n8;
    if (which == 0)      { in = x;  out = xo; n8 = (Mc * Dc) / 8; }
    else if (which == 1) { in = w0; out = o0; n8 = (Dc * Dc) / 8; }
    else if (which == 2) { in = w1; out = o1; n8 = (Dc * Dc) / 8; }
    else if (which == 3) { in = w2; out = o2; n8 = (Dc * Dc) / 8; }
    else                 { in = w3; out = o3; n8 = (Dc * Dc) / 8; }
    int i = blockIdx.x * 256 + threadIdx.x;
    if (i >= n8) return;
    cvt_body(in, out, i);
}

// --------------------------- NT GEMM, fused epilogues ------------------------
// C[M][N] = A[M][K] * W[N][K]^T + bias
// MODE 0: RoPE -> bf16 q (pre-scaled by QSCL)   MODE 1: RoPE -> bf16 k
// MODE 2: -> bf16 V^T [B][D][S]                 MODE 3: -> fp32 out
template <int MODE>
__global__ __launch_bounds__(256) void gemm_nt(
    const unsigned short* __restrict__ A, const unsigned short* __restrict__ W,
    const float* __restrict__ bias, const float* __restrict__ rc,
    const float* __restrict__ rs, void* __restrict__ outp) {
    __shared__ __align__(16) unsigned short As[128 * 64];
    __shared__ __align__(16) unsigned short Bs[128 * 64];
    const int tid = threadIdx.x;
    const int w = tid >> 6, l = tid & 63;
    const int wm = w >> 1, wn = w & 1;
    const int lrow = l & 15, lhi = l >> 4;
    const int m0 = blockIdx.y * 128, n0 = blockIdx.x * 128;

    f32x4 acc[4][4];
#pragma unroll
    for (int i = 0; i < 4; ++i)
#pragma unroll
        for (int j = 0; j < 4; ++j) acc[i][j] = (f32x4){0.f, 0.f, 0.f, 0.f};

    for (int k0 = 0; k0 < Kc; k0 += 64) {
        __syncthreads();
#pragma unroll
        for (int i = 0; i < 4; ++i) {
            int s = i * 256 + tid;
            int row = s >> 3, c = s & 7;
            int cg = (c ^ (row & 7)) * 8;      // pre-swizzled global source
            g2lds16(A + (size_t)(m0 + row) * Kc + k0 + cg,
                    &As[(size_t)(i * 256 + (w << 6)) * 8]);
            g2lds16(W + (size_t)(n0 + row) * Kc + k0 + cg,
                    &Bs[(size_t)(i * 256 + (w << 6)) * 8]);
        }
        __syncthreads();
#pragma unroll
        for (int kk = 0; kk < 2; ++kk) {
            short8 af[4], bf[4];
#pragma unroll
            for (int i = 0; i < 4; ++i) {
                int ra = wm * 64 + i * 16 + lrow;
                af[i] = *(const short8*)&As[ra * 64 + (((kk * 4 + lhi) ^ (ra & 7)) << 3)];
                int rb = wn * 64 + i * 16 + lrow;
                bf[i] = *(const short8*)&Bs[rb * 64 + (((kk * 4 + lhi) ^ (rb & 7)) << 3)];
            }
#pragma unroll
            for (int i = 0; i < 4; ++i)
#pragma unroll
                for (int j = 0; j < 4; ++j)
                    acc[i][j] = __builtin_amdgcn_mfma_f32_16x16x32_bf16(
                        af[i], bf[j], acc[i][j], 0, 0, 0);
        }
    }

#pragma unroll
    for (int i = 0; i < 4; ++i) {
#pragma unroll
        for (int j = 0; j < 4; ++j) {
            int gm0 = m0 + wm * 64 + i * 16 + lhi * 4;
            int gn  = n0 + wn * 64 + j * 16 + lrow;
            float bv = bias[gn];
            if (MODE == 0 || MODE == 1) {
                unsigned short* o = (unsigned short*)outp;
                int fi = (gn & (HDc - 1)) >> 1;
#pragma unroll
                for (int r = 0; r < 4; ++r) {
                    int gm = gm0 + r;
                    float v = acc[i][j][r] + bv;
                    float p = __shfl_xor(v, 1);          // partner column gn^1
                    int pos = gm & (Sc - 1);
                    float cz = rc[pos * (HDc / 2) + fi];
                    float sz = rs[pos * (HDc / 2) + fi];
                    float ov = (gn & 1) ? (p * sz + v * cz) : (v * cz - p * sz);
                    if (MODE == 0) ov *= QSCL;           // fold attn scale into q
                    o[(size_t)gm * Nc + gn] = f2bf(ov);
                }
            } else if (MODE == 2) {
                unsigned short* o = (unsigned short*)outp;   // V^T [B][D][S]
                int b = gm0 >> 11, sb = gm0 & (Sc - 1);
                u16x4 pk;
#pragma unroll
                for (int r = 0; r < 4; ++r) pk[r] = f2bf(acc[i][j][r] + bv);
                *(u16x4*)&o[((size_t)b * Dc + gn) * Sc + sb] = pk;
            } else {
                float* o = (float*)outp;
#pragma unroll
                for (int r = 0; r < 4; ++r)
                    o[(size_t)(gm0 + r) * Nc + gn] = acc[i][j][r] + bv;
            }
        }
    }
}

// --------------------------- causal flash attention (v5) ---------------------
// 512 blocks: (32 bh, 16 y), qt = y<8 ? y : 23-y  ->  co-resident pairs
// (id, id+256) are (qt, 15-qt): 34 tile-iters per CU, 2 blocks/CU = 2 w/SIMD.
// 4 waves x 32 q-rows; swapped QK^T 32x32 MFMA; ring-2 LDS, counted vmcnt.
// Cross-half reductions: __shfl_xor(.,32) (proven; permlane variant TBD).
__global__ __launch_bounds__(256, 2) void attn_fwd5(
    const unsigned short* __restrict__ Q, const unsigned short* __restrict__ Kb,
    const unsigned short* __restrict__ Vt, unsigned short* __restrict__ O) {
    __shared__ __align__(16) unsigned short Ks[2][64 * 128];
    __shared__ __align__(16) unsigned short Vs[2][128 * 64];
    const int tid = threadIdx.x;
    const int w = tid >> 6, l = tid & 63;
    const int ql = l & 31, Hh = l >> 5;
    const int bh = blockIdx.x;                 // 0..31
    const int y = blockIdx.y;                  // 0..15
    const int qt = (y < 8) ? y : (23 - y);     // co-location pairing
    const int b = bh >> 4, h = bh & 15;

    const unsigned short* Kbase = Kb + ((size_t)b * Sc) * Dc + h * HDc;
    const unsigned short* Vbase = Vt + ((size_t)b * Dc + h * HDc) * Sc;

#define STAGE(tt, kd, vd) {                                                    \
    const unsigned short* Kt = Kbase + (size_t)(tt) * 64 * Dc;                 \
    const unsigned short* Vp = Vbase + (tt) * 64;                              \
    _Pragma("unroll")                                                          \
    for (int i_ = 0; i_ < 4; ++i_) {                                           \
        int p_ = i_ * 256 + tid;                                               \
        int rK = p_ >> 4, sK = p_ & 15;                                        \
        g2lds16(Kt + (size_t)rK * Dc + ((sK ^ (rK & 15)) << 3),                \
                (kd) + (i_ * 256 + (w << 6)) * 8);                             \
        int rV = p_ >> 3, sV = p_ & 7;                                         \
        g2lds16(Vp + (size_t)rV * Sc + ((sV ^ (rV & 7)) << 3),                 \
                (vd) + (i_ * 256 + (w << 6)) * 8);                             \
    } }

#define PVSTEP(PC, HB, KS) {                                                   \
    int X0, X1, Y0, Y1;                                                        \
    asm("v_cvt_pk_bf16_f32 %0, %1, %2" : "=v"(X0) : "v"(PC[HB+0]), "v"(PC[HB+1])); \
    asm("v_cvt_pk_bf16_f32 %0, %1, %2" : "=v"(X1) : "v"(PC[HB+2]), "v"(PC[HB+3])); \
    asm("v_cvt_pk_bf16_f32 %0, %1, %2" : "=v"(Y0) : "v"(PC[HB+4]), "v"(PC[HB+5])); \
    asm("v_cvt_pk_bf16_f32 %0, %1, %2" : "=v"(Y1) : "v"(PC[HB+6]), "v"(PC[HB+7])); \
    asm("v_permlane32_swap_b32 %0, %1" : "+v"(X0), "+v"(Y0));                  \
    asm("v_permlane32_swap_b32 %0, %1" : "+v"(X1), "+v"(Y1));                  \
    union { int i[4]; short8 s; } pf_;                                         \
    pf_.i[0] = X0; pf_.i[1] = X1; pf_.i[2] = Y0; pf_.i[3] = Y1;                \
    _Pragma("unroll")                                                          \
    for (int dc_ = 0; dc_ < 4; ++dc_) {                                        \
        int rr = 32 * dc_ + ql;                                                \
        short8 vf = *(const short8*)&Vbuf[rr * 64 + (((2*(KS)+Hh) ^ (rr & 7)) << 3)]; \
        accv[dc_] = __builtin_amdgcn_mfma_f32_32x32x16_bf16(vf, pf_.s, accv[dc_], 0, 0, 0); \
    } }

    const int qw0 = qt * 128 + w * 32;
    const int qg = qw0 + ql;

    // Q fragments (already scaled by QSCL in gemm<0>)
    short8 qf[8];
    {
        const unsigned short* qp = Q + ((size_t)(b * Sc + qg)) * Dc + h * HDc;
#pragma unroll
        for (int dc = 0; dc < 8; ++dc)
            qf[dc] = *(const short8*)(qp + dc * 16 + Hh * 8);
    }
    f32x16 accv[4];
#pragma unroll
    for (int i = 0; i < 4; ++i) accv[i] = (f32x16)(0.f);
    float mrun = -3.0e38f, lrun = 0.f;
    const int nt = 2 * qt + 2;

    STAGE(0, Ks[0], Vs[0]);
    for (int t = 0; t < nt; ++t) {
        if (t + 1 < nt) {
            STAGE(t + 1, Ks[(t + 1) & 1], Vs[(t + 1) & 1]);
            asm volatile("s_waitcnt vmcnt(8)" ::: "memory");   // tile t landed
        } else {
            asm volatile("s_waitcnt vmcnt(0)" ::: "memory");
        }
        __builtin_amdgcn_s_barrier();          // all waves' tile-t loads visible

        const unsigned short* Kbuf = Ks[t & 1];
        const unsigned short* Vbuf = Vs[t & 1];
        const int kb0 = t * 64;
        if (kb0 <= qw0 + 31) {                 // wave has unmasked work
            // ---- QK^T (swapped): S^T[k][q], two 32-k subtiles ----
            f32x16 a0 = (f32x16)(0.f), a1 = (f32x16)(0.f);
            __builtin_amdgcn_s_setprio(1);
#pragma unroll
            for (int dc = 0; dc < 8; ++dc) {
                int r0 = ql, r1 = 32 + ql, sl = dc * 2 + Hh;
                short8 k0 = *(const short8*)&Kbuf[r0 * 128 + ((sl ^ (r0 & 15)) << 3)];
                short8 k1 = *(const short8*)&Kbuf[r1 * 128 + ((sl ^ (r1 & 15)) << 3)];
                a0 = __builtin_amdgcn_mfma_f32_32x32x16_bf16(k0, qf[dc], a0, 0, 0, 0);
                a1 = __builtin_amdgcn_mfma_f32_32x32x16_bf16(k1, qf[dc], a1, 0, 0, 0);
            }
            __builtin_amdgcn_s_setprio(0);
            if (t >= 2 * qt) {                 // boundary tile: causal mask
#pragma unroll
                for (int r = 0; r < 16; ++r) {
                    int kl = (r & 3) + 8 * (r >> 2) + 4 * Hh;
                    if (kb0 + kl > qg)      a0[r] = -3.0e38f;
                    if (kb0 + 32 + kl > qg) a1[r] = -3.0e38f;
                }
            }
            // ---- online softmax, lane-local; tree max; defer-max (THR=8) ----
            float m8[8];
#pragma unroll
            for (int r = 0; r < 8; ++r)
                m8[r] = fmaxf(fmaxf(a0[r], a0[r + 8]), fmaxf(a1[r], a1[r + 8]));
            float m4a = fmaxf(m8[0], m8[1]), m4b = fmaxf(m8[2], m8[3]);
            float m4c = fmaxf(m8[4], m8[5]), m4d = fmaxf(m8[6], m8[7]);
            float pm = fmaxf(fmaxf(m4a, m4b), fmaxf(m4c, m4d));
            pm = fmaxf(pm, __shfl_xor(pm, 32));
            if (!__all(pm - mrun <= 8.0f)) {
                float mnew = fmaxf(mrun, pm);
                float fs = exp2f(mrun - mnew);
                mrun = mnew;
                lrun *= fs;
#pragma unroll
                for (int dc = 0; dc < 4; ++dc)
#pragma unroll
                    for (int r = 0; r < 16; ++r) accv[dc][r] *= fs;
            }
            float p0[16], p1[16];
#pragma unroll
            for (int r = 0; r < 16; ++r) p0[r] = exp2f(a0[r] - mrun);
#pragma unroll
            for (int r = 0; r < 16; ++r) p1[r] = exp2f(a1[r] - mrun);
            float s8[8];
#pragma unroll
            for (int r = 0; r < 8; ++r)
                s8[r] = (p0[r] + p0[r + 8]) + (p1[r] + p1[r + 8]);
            float s4a = s8[0] + s8[1], s4b = s8[2] + s8[3];
            float s4c = s8[4] + s8[5], s4d = s8[6] + s8[7];
            float ps = (s4a + s4b) + (s4c + s4d);
            lrun += ps + __shfl_xor(ps, 32);
            // ---- PV: O^T += V^T . P^T  (4 k-steps of 16) ----
            __builtin_amdgcn_s_setprio(1);
            PVSTEP(p0, 0, 0); PVSTEP(p0, 8, 1);
            PVSTEP(p1, 0, 2); PVSTEP(p1, 8, 3);
            __builtin_amdgcn_s_setprio(0);
        }
        __builtin_amdgcn_s_barrier();          // done reading buf t&1
    }
    // ---- epilogue: O^T -> O, /l, bf16 ----
    float inv = 1.f / lrun;
    unsigned short* Op = O + ((size_t)(b * Sc + qg)) * Dc + h * HDc;
#pragma unroll
    for (int dc = 0; dc < 4; ++dc)
#pragma unroll
        for (int rg = 0; rg < 4; ++rg) {
            int d0 = 32 * dc + 8 * rg + 4 * Hh;
            u16x4 pk;
#pragma unroll
            for (int j = 0; j < 4; ++j) pk[j] = f2bf(accv[dc][rg * 4 + j] * inv);
            *(u16x4*)(Op + d0) = pk;
        }
#undef STAGE
#undef PVSTEP
}

// ------------------------------- launcher -----------------------------------
extern "C" void kernel_launch(void* const* d_in, const int* in_sizes, int n_in,
                              void* d_out, int out_size, void* d_ws, size_t ws_size,
                              hipStream_t stream) {
    const float* x  = (const float*)d_in[0];
    const float* wq = (const float*)d_in[1];
    const float* bq = (const float*)d_in[2];
    const float* wk = (const float*)d_in[3];
    const float* bk = (const float*)d_in[4];
    const float* wv = (const float*)d_in[5];
    const float* bv = (const float*)d_in[6];
    const float* wo = (const float*)d_in[7];
    const float* bo = (const float*)d_in[8];
    const float* rc = (const float*)d_in[9];
    const float* rs = (const float*)d_in[10];

    const size_t NE = (size_t)Mc * Dc;  // 8.4M elems (x / q / k / v / o each)
    const size_t NW = (size_t)Dc * Dc;  // 4.2M elems (one weight)

    unsigned short* xb = (unsigned short*)d_ws;  // x bf16; reused as attn out
    unsigned short* qb = xb + NE;
    unsigned short* kb = qb + NE;
    unsigned short* vt = kb + NE;                // V^T [B][D][S]
    unsigned short* wb = vt + NE;                // weight buffer(s)

    const int ne8 = (int)(NE / 8), nw8 = (int)(NW / 8);
    dim3 gg(Nc / 128, Mc / 128), tb(256);
    const bool big_ws = ws_size >= (4 * NE + 4 * NW) * sizeof(unsigned short);

    if (big_ws) {
        unsigned short* wqb = wb;
        unsigned short* wkb = wb + NW;
        unsigned short* wvb = wb + 2 * NW;
        unsigned short* wob = wb + 3 * NW;
        cvt_batch<<<dim3(ne8 / 256, 5), tb, 0, stream>>>(
            x, xb, wq, wqb, wk, wkb, wv, wvb, wo, wob);
        gemm_nt<0><<<gg, tb, 0, stream>>>(xb, wqb, bq, rc, rs, qb);
        gemm_nt<1><<<gg, tb, 0, stream>>>(xb, wkb, bk, rc, rs, kb);
        gemm_nt<2><<<gg, tb, 0, stream>>>(xb, wvb, bv, rc, rs, vt);
        attn_fwd5<<<dim3(Bc * Hc, 16), tb, 0, stream>>>(qb, kb, vt, xb);
        gemm_nt<3><<<gg, tb, 0, stream>>>(xb, wob, bo, rc, rs, d_out);
    } else {
        cvt_f32_bf16<<<dim3(ne8 / 256), tb, 0, stream>>>(x, xb, ne8);
        cvt_f32_bf16<<<dim3(nw8 / 256), tb, 0, stream>>>(wq, wb, nw8);
        gemm_nt<0><<<gg, tb, 0, stream>>>(xb, wb, bq, rc, rs, qb);
        cvt_f32_bf16<<<dim3(nw8 / 256), tb, 0, stream>>>(wk, wb, nw8);
        gemm_nt<1><<<gg, tb, 0, stream>>>(xb, wb, bk, rc, rs, kb);
        cvt_f32_bf16<<<dim3(nw8 / 256), tb, 0, stream>>>(wv, wb, nw8);
        gemm_nt<2><<<gg, tb, 0, stream>>>(xb, wb, bv, rc, rs, vt);
        attn_fwd5<<<dim3(Bc * Hc, 16), tb, 0, stream>>>(qb, kb, vt, xb);
        cvt_f32_bf16<<<dim3(nw8 / 256), tb, 0, stream>>>(wo, wb, nw8);
        gemm_nt<3><<<gg, tb, 0, stream>>>(xb, wb, bo, rc, rs, d_out);
    }
}